// Round 1
// baseline (822.666 us; speedup 1.0000x reference)
//
#include <hip/hip_runtime.h>
#include <hip/hip_bf16.h>
#include <stdint.h>

#define D_MODEL 2048
#define D_FF    8192
#define NTOK    4096
#define WSCALE  0.02f

using bf16 = __hip_bfloat16;
typedef __bf16 bf16x8 __attribute__((ext_vector_type(8)));
typedef float  f32x4  __attribute__((ext_vector_type(4)));

// async global -> LDS, 16 B per lane (wave-uniform base + lane*16 layout)
__device__ __forceinline__ void gld_lds16(const bf16* g, bf16* l) {
    __builtin_amdgcn_global_load_lds((const __attribute__((address_space(1))) void*)g,
                                     (__attribute__((address_space(3))) void*)l,
                                     16, 0, 0);
}

// ---------------- dequant: W[r][c] = lut[walks[r][c]] * sl[r] * sr[c] * 0.02 ----------------
__global__ __launch_bounds__(256) void dequant_kernel(const int* __restrict__ walks,
                                                      const float* __restrict__ lut,
                                                      const float* __restrict__ sl,
                                                      const float* __restrict__ sr,
                                                      bf16* __restrict__ W,
                                                      int colsLog2) {
    __shared__ float slut[256];
    slut[threadIdx.x] = lut[threadIdx.x] * WSCALE;
    __syncthreads();
    long base = ((long)blockIdx.x * 256 + threadIdx.x) * 8;
    int r = (int)(base >> colsLog2);
    int c = (int)(base & ((1 << colsLog2) - 1));
    float s = sl[r];
    const int4* wp = (const int4*)(walks + base);
    int4 w0 = wp[0];
    int4 w1 = wp[1];
    float4 s0 = *(const float4*)(sr + c);
    float4 s1 = *(const float4*)(sr + c + 4);
    alignas(16) bf16 o[8];
    o[0] = __float2bfloat16(slut[w0.x] * s0.x * s);
    o[1] = __float2bfloat16(slut[w0.y] * s0.y * s);
    o[2] = __float2bfloat16(slut[w0.z] * s0.z * s);
    o[3] = __float2bfloat16(slut[w0.w] * s0.w * s);
    o[4] = __float2bfloat16(slut[w1.x] * s1.x * s);
    o[5] = __float2bfloat16(slut[w1.y] * s1.y * s);
    o[6] = __float2bfloat16(slut[w1.z] * s1.z * s);
    o[7] = __float2bfloat16(slut[w1.w] * s1.w * s);
    *(uint4*)(W + base) = *(const uint4*)o;
}

// ---------------- x fp32 -> bf16 ----------------
__global__ __launch_bounds__(256) void cvt_bf16_kernel(const float* __restrict__ X,
                                                       bf16* __restrict__ Y) {
    long base = ((long)blockIdx.x * 256 + threadIdx.x) * 8;
    float4 a = *(const float4*)(X + base);
    float4 b = *(const float4*)(X + base + 4);
    alignas(16) bf16 o[8];
    o[0] = __float2bfloat16(a.x);
    o[1] = __float2bfloat16(a.y);
    o[2] = __float2bfloat16(a.z);
    o[3] = __float2bfloat16(a.w);
    o[4] = __float2bfloat16(b.x);
    o[5] = __float2bfloat16(b.y);
    o[6] = __float2bfloat16(b.z);
    o[7] = __float2bfloat16(b.w);
    *(uint4*)(Y + base) = *(const uint4*)o;
}

// ---------------- GEMM: C[M,N] = A[M,K] @ B[N,K]^T  (both row-major, K-contiguous) ----------
// 128x128 tile / block, 256 threads = 4 waves (2x2 of 64x64), BK=32, 16x16x32 bf16 MFMA.
// EPI 0: G = bf16(silu(C));  EPI 1: G *= C (in place, bf16);  EPI 2: Out = C (fp32)
template<int EPI>
__global__ __launch_bounds__(256) void gemm_bt(const bf16* __restrict__ A,
                                               const bf16* __restrict__ B,
                                               bf16* __restrict__ G,
                                               float* __restrict__ Out,
                                               int N, int K) {
    __shared__ alignas(16) bf16 As[128 * 32];   // 8 KB, row-major [row][k], no padding
    __shared__ alignas(16) bf16 Bs[128 * 32];   // 8 KB

    const int t = threadIdx.x;
    const int mBase = blockIdx.y * 128;
    const int nBase = blockIdx.x * 128;

    // staging: thread t covers (row = t>>2 [+64]), 8 bf16 at col (t&3)*8
    const int rowA = t >> 2;
    const int colO = (t & 3) * 8;
    const bf16* Ag = A + (long)(mBase + rowA) * K + colO;
    const bf16* Bg = B + (long)(nBase + rowA) * K + colO;
    const long rstep = (long)64 * K;

    f32x4 acc[4][4];
#pragma unroll
    for (int i = 0; i < 4; i++)
#pragma unroll
        for (int j = 0; j < 4; j++) {
            f32x4 z = {0.f, 0.f, 0.f, 0.f};
            acc[i][j] = z;
        }

    const int lane  = t & 63;
    const int wave  = t >> 6;
    const int waveM = (wave & 1) * 64;
    const int waveN = (wave >> 1) * 64;
    const int m16   = lane & 15;
    const int kq    = (lane >> 4) * 8;
    const bf16* Asr = &As[(waveM + m16) * 32 + kq];
    const bf16* Bsr = &Bs[(waveN + m16) * 32 + kq];

    for (int k0 = 0; k0 < K; k0 += 32) {
        gld_lds16(Ag + k0,         &As[t * 8]);
        gld_lds16(Ag + k0 + rstep, &As[2048 + t * 8]);
        gld_lds16(Bg + k0,         &Bs[t * 8]);
        gld_lds16(Bg + k0 + rstep, &Bs[2048 + t * 8]);
        __syncthreads();   // compiler emits vmcnt(0) drain before s_barrier

        bf16x8 af[4], bfr[4];
#pragma unroll
        for (int i = 0; i < 4; i++) af[i]  = *(const bf16x8*)(Asr + i * 16 * 32);
#pragma unroll
        for (int j = 0; j < 4; j++) bfr[j] = *(const bf16x8*)(Bsr + j * 16 * 32);
#pragma unroll
        for (int i = 0; i < 4; i++)
#pragma unroll
            for (int j = 0; j < 4; j++)
                acc[i][j] = __builtin_amdgcn_mfma_f32_16x16x32_bf16(af[i], bfr[j], acc[i][j], 0, 0, 0);
        __syncthreads();
    }

    // epilogue: D[reg] -> row = (lane>>4)*4+reg, col = lane&15  (m89-verified mapping)
    const int rq = (lane >> 4) * 4;
#pragma unroll
    for (int i = 0; i < 4; i++) {
#pragma unroll
        for (int j = 0; j < 4; j++) {
#pragma unroll
            for (int r = 0; r < 4; r++) {
                int grow = mBase + waveM + i * 16 + rq + r;
                int gcol = nBase + waveN + j * 16 + m16;
                long idx = (long)grow * N + gcol;
                float v = acc[i][j][r];
                if (EPI == 0) {
                    float sv = v / (1.0f + __expf(-v));
                    G[idx] = __float2bfloat16(sv);
                } else if (EPI == 1) {
                    float gv = __bfloat162float(G[idx]);
                    G[idx] = __float2bfloat16(gv * v);
                } else {
                    Out[idx] = v;
                }
            }
        }
    }
}

extern "C" void kernel_launch(void* const* d_in, const int* in_sizes, int n_in,
                              void* d_out, int out_size, void* d_ws, size_t ws_size,
                              hipStream_t stream) {
    (void)in_sizes; (void)n_in; (void)out_size; (void)ws_size;
    const float* x     = (const float*)d_in[0];
    const float* lut_g = (const float*)d_in[1];
    const float* lut_u = (const float*)d_in[2];
    const float* lut_d = (const float*)d_in[3];
    const int*   wk_g  = (const int*)d_in[4];
    const int*   wk_u  = (const int*)d_in[5];
    const int*   wk_d  = (const int*)d_in[6];
    const float* sl_g  = (const float*)d_in[7];
    const float* sr_g  = (const float*)d_in[8];
    const float* sl_u  = (const float*)d_in[9];
    const float* sr_u  = (const float*)d_in[10];
    const float* sl_d  = (const float*)d_in[11];
    const float* sr_d  = (const float*)d_in[12];

    char* ws = (char*)d_ws;
    bf16* xb = (bf16*)(ws);                                   // 16 MB
    bf16* Wg = (bf16*)(ws + (size_t)16 * 1024 * 1024);        // 32 MB
    bf16* Wu = (bf16*)(ws + (size_t)48 * 1024 * 1024);        // 32 MB
    bf16* G  = (bf16*)(ws + (size_t)80 * 1024 * 1024);        // 64 MB -> ws peak 144 MB
    bf16* Wd = Wg;                                            // reuse Wg slot after gate GEMM
    float* out = (float*)d_out;

    cvt_bf16_kernel<<<dim3(NTOK * D_MODEL / 2048), 256, 0, stream>>>(x, xb);
    dequant_kernel<<<dim3(D_FF * D_MODEL / 2048), 256, 0, stream>>>(wk_g, lut_g, sl_g, sr_g, Wg, 11);
    dequant_kernel<<<dim3(D_FF * D_MODEL / 2048), 256, 0, stream>>>(wk_u, lut_u, sl_u, sr_u, Wu, 11);

    // gate: [4096,8192] = xb @ Wg^T, fused silu -> G (bf16)
    gemm_bt<0><<<dim3(D_FF / 128, NTOK / 128), 256, 0, stream>>>(xb, Wg, G, nullptr, D_FF, D_MODEL);
    // up: G *= xb @ Wu^T  (in place)
    gemm_bt<1><<<dim3(D_FF / 128, NTOK / 128), 256, 0, stream>>>(xb, Wu, G, nullptr, D_FF, D_MODEL);

    dequant_kernel<<<dim3(D_MODEL * D_FF / 2048), 256, 0, stream>>>(wk_d, lut_d, sl_d, sr_d, Wd, 13);
    // down: out[4096,2048] = G @ Wd^T (fp32 out)
    gemm_bt<2><<<dim3(D_MODEL / 128, NTOK / 128), 256, 0, stream>>>(G, Wd, nullptr, out, D_MODEL, D_FF);
}